// Round 7
// baseline (68.596 us; speedup 1.0000x reference)
//
#include <hip/hip_runtime.h>
#include <stdint.h>
#include <math.h>

constexpr int SEQ   = 512;
constexpr int BATCH = 2048;
constexpr int EMB   = 50;
constexpr int NBCLS = 2;
constexpr int VOCAB = 100000;
constexpr int NTHR  = 512;
constexpr int TPAD  = 32;   // uints per padded bf16 table row (64 bf16 = 128 B = 1 line)

__device__ __forceinline__ uint32_t f32_to_bf16_rne(float f) {
    uint32_t u = __float_as_uint(f);
    return (u + 0x7fffu + ((u >> 16) & 1u)) >> 16;
}
__device__ __forceinline__ float bf16_lo(uint32_t u) { return __uint_as_float(u << 16); }
__device__ __forceinline__ float bf16_hi(uint32_t u) { return __uint_as_float(u & 0xffff0000u); }

// ---- merged prologue: table->bf16-padded + x transpose + Wq/We transpose
constexpr int CONV_BLOCKS = VOCAB * TPAD / 256;        // 12500
constexpr int TR_BLOCKS   = (SEQ / 32) * (BATCH / 32); // 1024

__global__ __launch_bounds__(256) void prologue(
    const float* __restrict__ t, uint32_t* __restrict__ o,
    const int* __restrict__ x, int* __restrict__ xT,
    const float* __restrict__ Wq, const float* __restrict__ We,
    float* __restrict__ WqT, float* __restrict__ WeT)
{
    __shared__ int tile[32][33];
    const int bid = blockIdx.x, tid = threadIdx.x;
    if (bid < CONV_BLOCKS) {
        int idx = bid * 256 + tid;               // VOCAB*32 exact
        int v = idx >> 5, c = idx & 31;
        uint32_t val = 0;
        if (c < 25) {
            float2 f = *reinterpret_cast<const float2*>(t + (long)v * EMB + 2 * c);
            val = f32_to_bf16_rne(f.x) | (f32_to_bf16_rne(f.y) << 16);
        }
        o[(long)v * TPAD + c] = val;
    } else if (bid < CONV_BLOCKS + TR_BLOCKS) {
        int b2 = bid - CONV_BLOCKS;              // 0..1023
        int s0 = (b2 & 15) * 32, b0 = (b2 >> 4) * 32;
        int tx = tid & 31, ty = tid >> 5;        // 32 x 8
        #pragma unroll
        for (int j = 0; j < 32; j += 8) tile[ty + j][tx] = x[(s0 + ty + j) * BATCH + b0 + tx];
        __syncthreads();
        #pragma unroll
        for (int j = 0; j < 32; j += 8) xT[(b0 + ty + j) * SEQ + s0 + tx] = tile[tx][ty + j];
    } else {
        for (int idx = tid; idx < EMB * EMB; idx += 256) {
            int i = idx / EMB, j = idx - i * EMB;
            WqT[j * EMB + i] = Wq[idx];
            WeT[j * EMB + i] = We[idx];
        }
    }
}

// ---- main: one block per batch element.
// LINE-COALESCED gather: lane l reads 16B chunk (l&7) of row group (l>>3);
// each wave-load touches 8 cache lines (not 64). 8 iterations cover 512 rows.
// Rows are distributed across 8-lane groups; reductions are lane butterflies.
__global__ __launch_bounds__(NTHR) void attn_main(
    const int*      __restrict__ xT,    // [BATCH][SEQ]
    const uint32_t* __restrict__ tbl,   // [VOCAB][TPAD] packed bf16 pairs
    const float* __restrict__ WqT, const float* __restrict__ bq,
    const float* __restrict__ WeT, const float* __restrict__ be,
    const float* __restrict__ Wo,  const float* __restrict__ bo,
    float* __restrict__ out_yhat, float* __restrict__ out_att)
{
    const int b    = blockIdx.x;
    const int tid  = threadIdx.x;
    const int lane = tid & 63;
    const int wave = tid >> 6;
    const int k    = lane >> 3;          // row-within-group 0..7
    const int c    = lane & 7;           // 16B chunk 0..7 (bf16 cols 8c..8c+7)

    __shared__ int   toks[SEQ];          // 2 KB
    __shared__ float att_lds[SEQ];       // 2 KB
    __shared__ float p2[8 * 64];         // [wave][64 cols], 2 KB
    __shared__ float meanv[64];          // mean, then pooled
    __shared__ float qv[64];             // q, then We-output
    __shared__ float red[8];

    // ---- tokens (coalesced)
    toks[tid] = xT[(long)b * SEQ + tid];
    __syncthreads();

    // ---- gather: 8 iterations, one 16B chunk each; wave-load = 8 lines
    uint4 d[8];
    #pragma unroll
    for (int i = 0; i < 8; ++i) {
        int r = i * 64 + wave * 8 + k;
        long tok = toks[r];
        d[i] = *reinterpret_cast<const uint4*>(tbl + tok * TPAD + (c << 2));
    }

    // ---- mean: per-thread 8-col accum over its 64 rows, then xor8/16/32
    float acc[8];
    #pragma unroll
    for (int j = 0; j < 8; ++j) acc[j] = 0.f;
    #pragma unroll
    for (int i = 0; i < 8; ++i) {
        uint32_t u0 = d[i].x, u1 = d[i].y, u2 = d[i].z, u3 = d[i].w;
        acc[0] += bf16_lo(u0); acc[1] += bf16_hi(u0);
        acc[2] += bf16_lo(u1); acc[3] += bf16_hi(u1);
        acc[4] += bf16_lo(u2); acc[5] += bf16_hi(u2);
        acc[6] += bf16_lo(u3); acc[7] += bf16_hi(u3);
    }
    #pragma unroll
    for (int j = 0; j < 8; ++j) {
        acc[j] += __shfl_xor(acc[j], 8);
        acc[j] += __shfl_xor(acc[j], 16);
        acc[j] += __shfl_xor(acc[j], 32);
    }
    if (lane < 8) {                      // lane==c holds cols 8c..8c+7 sums
        *reinterpret_cast<float4*>(&p2[wave * 64 + lane * 8])     = make_float4(acc[0], acc[1], acc[2], acc[3]);
        *reinterpret_cast<float4*>(&p2[wave * 64 + lane * 8 + 4]) = make_float4(acc[4], acc[5], acc[6], acc[7]);
    }
    __syncthreads();
    if (tid < 64) {
        float s = 0.f;
        #pragma unroll
        for (int w = 0; w < 8; ++w) s += p2[w * 64 + tid];
        meanv[tid] = s * (1.0f / SEQ);
    }
    __syncthreads();

    // ---- q = mean @ Wq.T + bq ; qv[50..63] = 0
    if (tid < EMB) {
        float a = bq[tid];
        #pragma unroll 5
        for (int e = 0; e < EMB; ++e) a += meanv[e] * WqT[e * EMB + tid];
        qv[tid] = a;
    } else if (tid < 64) {
        qv[tid] = 0.f;
    }
    __syncthreads();

    // ---- register-cache q chunk (reused across all 8 iterations)
    float qreg[8];
    {
        float4 q0 = *reinterpret_cast<const float4*>(&qv[c * 8]);
        float4 q1 = *reinterpret_cast<const float4*>(&qv[c * 8 + 4]);
        qreg[0]=q0.x; qreg[1]=q0.y; qreg[2]=q0.z; qreg[3]=q0.w;
        qreg[4]=q1.x; qreg[5]=q1.y; qreg[6]=q1.z; qreg[7]=q1.w;
    }

    // ---- scores: per-iteration partial dot + xor1/2/4 within 8-lane group
    float sc[8];
    #pragma unroll
    for (int i = 0; i < 8; ++i) {
        uint32_t u0 = d[i].x, u1 = d[i].y, u2 = d[i].z, u3 = d[i].w;
        float p = bf16_lo(u0) * qreg[0] + bf16_hi(u0) * qreg[1]
                + bf16_lo(u1) * qreg[2] + bf16_hi(u1) * qreg[3]
                + bf16_lo(u2) * qreg[4] + bf16_hi(u2) * qreg[5]
                + bf16_lo(u3) * qreg[6] + bf16_hi(u3) * qreg[7];
        p += __shfl_xor(p, 1);
        p += __shfl_xor(p, 2);
        p += __shfl_xor(p, 4);
        sc[i] = p;                       // score of row i*64+wave*8+k (replicated over c)
    }

    // ---- softmax over 512
    float m = sc[0];
    #pragma unroll
    for (int i = 1; i < 8; ++i) m = fmaxf(m, sc[i]);
    m = fmaxf(m, __shfl_xor(m, 8));
    m = fmaxf(m, __shfl_xor(m, 16));
    m = fmaxf(m, __shfl_xor(m, 32));
    if (lane == 0) red[wave] = m;
    __syncthreads();
    if (tid == 0) {
        float mm = red[0];
        #pragma unroll
        for (int w = 1; w < 8; ++w) mm = fmaxf(mm, red[w]);
        red[0] = mm;
    }
    __syncthreads();
    const float maxv = red[0];
    float ex[8];
    float s_loc = 0.f;
    #pragma unroll
    for (int i = 0; i < 8; ++i) { ex[i] = __expf(sc[i] - maxv); s_loc += ex[i]; }
    __syncthreads();                     // red[0] consumed before reuse
    s_loc += __shfl_xor(s_loc, 8);
    s_loc += __shfl_xor(s_loc, 16);
    s_loc += __shfl_xor(s_loc, 32);      // wave total (each row counted once)
    if (lane == 0) red[wave] = s_loc;
    __syncthreads();
    if (tid == 0) {
        float t = 0.f;
        #pragma unroll
        for (int w = 0; w < 8; ++w) t += red[w];
        red[0] = 1.0f / t;
    }
    __syncthreads();
    const float inv = red[0];

    // ---- att: thread-local per iteration; stage to LDS for coalesced write
    float at[8];
    #pragma unroll
    for (int i = 0; i < 8; ++i) {
        at[i] = ex[i] * inv;
        if (c == 0) att_lds[i * 64 + wave * 8 + k] = at[i];
    }
    __syncthreads();
    out_att[(long)b * SEQ + tid] = att_lds[tid];

    // ---- pool: att-weighted accum, same reduction as mean
    #pragma unroll
    for (int j = 0; j < 8; ++j) acc[j] = 0.f;
    #pragma unroll
    for (int i = 0; i < 8; ++i) {
        uint32_t u0 = d[i].x, u1 = d[i].y, u2 = d[i].z, u3 = d[i].w;
        float a = at[i];
        acc[0] += a * bf16_lo(u0); acc[1] += a * bf16_hi(u0);
        acc[2] += a * bf16_lo(u1); acc[3] += a * bf16_hi(u1);
        acc[4] += a * bf16_lo(u2); acc[5] += a * bf16_hi(u2);
        acc[6] += a * bf16_lo(u3); acc[7] += a * bf16_hi(u3);
    }
    #pragma unroll
    for (int j = 0; j < 8; ++j) {
        acc[j] += __shfl_xor(acc[j], 8);
        acc[j] += __shfl_xor(acc[j], 16);
        acc[j] += __shfl_xor(acc[j], 32);
    }
    if (lane < 8) {
        *reinterpret_cast<float4*>(&p2[wave * 64 + lane * 8])     = make_float4(acc[0], acc[1], acc[2], acc[3]);
        *reinterpret_cast<float4*>(&p2[wave * 64 + lane * 8 + 4]) = make_float4(acc[4], acc[5], acc[6], acc[7]);
    }
    __syncthreads();
    if (tid < 64) {
        float s = 0.f;
        #pragma unroll
        for (int w = 0; w < 8; ++w) s += p2[w * 64 + tid];
        meanv[tid] = s;                  // pooled
    }
    __syncthreads();

    // ---- pooled @ We.T + be  (sum(att)=1 => be exact)
    if (tid < EMB) {
        float a = be[tid];
        #pragma unroll 5
        for (int e = 0; e < EMB; ++e) a += meanv[e] * WeT[e * EMB + tid];
        qv[tid] = a;
    }
    __syncthreads();

    // ---- yhat: wave 0, coalesced Wo reads, wave reduce
    if (wave == 0) {
        float pv = (lane < EMB) ? qv[lane] : 0.f;
        float a0 = (lane < EMB) ? pv * Wo[lane]       : 0.f;
        float a1 = (lane < EMB) ? pv * Wo[EMB + lane] : 0.f;
        #pragma unroll
        for (int off = 1; off < 64; off <<= 1) {
            a0 += __shfl_xor(a0, off);
            a1 += __shfl_xor(a1, off);
        }
        if (lane == 0) {
            out_yhat[(long)b * NBCLS + 0] = a0 + bo[0];
            out_yhat[(long)b * NBCLS + 1] = a1 + bo[1];
        }
    }
}

// ---- fallback (ws too small): round-1 f32 kernel
__global__ __launch_bounds__(NTHR) void attn_fused_f32(
    const int*   __restrict__ x,
    const float* __restrict__ table,
    const float* __restrict__ Wq, const float* __restrict__ bq,
    const float* __restrict__ We, const float* __restrict__ be,
    const float* __restrict__ Wo, const float* __restrict__ bo,
    float* __restrict__ out_yhat, float* __restrict__ out_att)
{
    const int b   = blockIdx.x;
    const int tid = threadIdx.x;

    __shared__ float emb[SEQ * EMB];
    __shared__ int   toks[SEQ];
    __shared__ float scores[SEQ];
    __shared__ float red[8];
    __shared__ float partials[8 * EMB];
    __shared__ float meanv[EMB];
    __shared__ float qv[EMB];
    __shared__ float pooled[EMB];

    toks[tid] = x[tid * BATCH + b];
    __syncthreads();
    for (int idx = tid; idx < SEQ * (EMB / 2); idx += NTHR) {
        int s = idx / 25, e2 = idx - s * 25;
        long t = toks[s];
        float2 v = *reinterpret_cast<const float2*>(table + t * EMB + e2 * 2);
        *reinterpret_cast<float2*>(emb + s * EMB + e2 * 2) = v;
    }
    __syncthreads();
    if (tid < 8 * EMB) {
        int e = tid % EMB, cc = tid / EMB, s0 = cc * 64;
        float acc = 0.f;
        for (int i = 0; i < 64; ++i) acc += emb[(s0 + i) * EMB + e];
        partials[cc * EMB + e] = acc;
    }
    __syncthreads();
    if (tid < EMB) {
        float acc = 0.f;
        for (int cc = 0; cc < 8; ++cc) acc += partials[cc * EMB + tid];
        meanv[tid] = acc * (1.0f / SEQ);
    }
    __syncthreads();
    if (tid < EMB) {
        float acc = bq[tid];
        const float* wrow = Wq + tid * EMB;
        for (int e = 0; e < EMB; ++e) acc += meanv[e] * wrow[e];
        qv[tid] = acc;
    }
    __syncthreads();
    {
        const float* rowp = emb + tid * EMB;
        float acc = 0.f;
        for (int e = 0; e < EMB; ++e) acc += qv[e] * rowp[e];
        scores[tid] = acc;
    }
    __syncthreads();
    const int lane = tid & 63, wave = tid >> 6;
    float v = scores[tid];
    float m = v;
    for (int off = 1; off < 64; off <<= 1) m = fmaxf(m, __shfl_xor(m, off));
    if (lane == 0) red[wave] = m;
    __syncthreads();
    if (tid == 0) {
        float mm = red[0];
        for (int w = 1; w < 8; ++w) mm = fmaxf(mm, red[w]);
        red[0] = mm;
    }
    __syncthreads();
    const float maxv = red[0];
    const float ex = __expf(v - maxv);
    __syncthreads();
    float ssum = ex;
    for (int off = 1; off < 64; off <<= 1) ssum += __shfl_xor(ssum, off);
    if (lane == 0) red[wave] = ssum;
    __syncthreads();
    if (tid == 0) {
        float t = 0.f;
        for (int w = 0; w < 8; ++w) t += red[w];
        red[0] = 1.0f / t;
    }
    __syncthreads();
    const float att = ex * red[0];
    scores[tid] = att;
    out_att[(long)b * SEQ + tid] = att;
    __syncthreads();
    if (tid < 8 * EMB) {
        int e = tid % EMB, cc = tid / EMB, s0 = cc * 64;
        float acc = 0.f;
        for (int i = 0; i < 64; ++i) acc += scores[s0 + i] * emb[(s0 + i) * EMB + e];
        partials[cc * EMB + e] = acc;
    }
    __syncthreads();
    if (tid < EMB) {
        float acc = 0.f;
        for (int cc = 0; cc < 8; ++cc) acc += partials[cc * EMB + tid];
        pooled[tid] = acc;
    }
    __syncthreads();
    if (tid < EMB) {
        float acc = be[tid];
        const float* wrow = We + tid * EMB;
        for (int e = 0; e < EMB; ++e) acc += pooled[e] * wrow[e];
        qv[tid] = acc;
    }
    __syncthreads();
    if (tid < NBCLS) {
        float acc = bo[tid];
        const float* wrow = Wo + tid * EMB;
        for (int e = 0; e < EMB; ++e) acc += qv[e] * wrow[e];
        out_yhat[(long)b * NBCLS + tid] = acc;
    }
}

extern "C" void kernel_launch(void* const* d_in, const int* in_sizes, int n_in,
                              void* d_out, int out_size, void* d_ws, size_t ws_size,
                              hipStream_t stream) {
    // inputs: x, x_lengths, mask, emb_table, Wq, bq, We, be, Wo, bo
    const int*   x     = (const int*)  d_in[0];
    const float* table = (const float*)d_in[3];
    const float* Wq    = (const float*)d_in[4];
    const float* bq    = (const float*)d_in[5];
    const float* We    = (const float*)d_in[6];
    const float* be    = (const float*)d_in[7];
    const float* Wo    = (const float*)d_in[8];
    const float* bo    = (const float*)d_in[9];

    float* out_yhat = (float*)d_out;
    float* out_att  = (float*)d_out + (long)BATCH * NBCLS;

    const size_t tbl_bytes = (size_t)VOCAB * TPAD * 4;          // 12.8 MB
    const size_t xt_bytes  = (size_t)BATCH * SEQ * 4;           // 4 MB
    const size_t w_bytes   = (size_t)EMB * EMB * 4;             // 10 KB each

    if (ws_size >= tbl_bytes + xt_bytes + 2 * w_bytes) {
        uint32_t* tbl16 = (uint32_t*)d_ws;
        int*      xT    = (int*)((char*)d_ws + tbl_bytes);
        float*    WqT   = (float*)((char*)d_ws + tbl_bytes + xt_bytes);
        float*    WeT   = (float*)((char*)d_ws + tbl_bytes + xt_bytes + w_bytes);
        prologue<<<CONV_BLOCKS + TR_BLOCKS + 1, 256, 0, stream>>>(
            table, tbl16, x, xT, Wq, We, WqT, WeT);
        attn_main<<<BATCH, NTHR, 0, stream>>>(xT, tbl16, WqT, bq, WeT, be, Wo, bo,
                                              out_yhat, out_att);
    } else {
        attn_fused_f32<<<BATCH, NTHR, 0, stream>>>(x, table, Wq, bq, We, be, Wo, bo,
                                                   out_yhat, out_att);
    }
}